// Round 1
// baseline (103.192 us; speedup 1.0000x reference)
//
#include <hip/hip_runtime.h>

#define N 16384
#define K_ACTIVE 50
#define MAT_BIT (1 << 14)

// ws layout:
//   [0..255]        : int counter (ncomb) + padding
//   [256 .. 256+64K): float y[N]
//   [256+64K .. )   : int list[] (encoded active columns)

__global__ void init_counter(int* cnt) {
    if (threadIdx.x == 0) cnt[0] = 0;
}

__global__ void build_list(const float* __restrict__ x,
                           const float* __restrict__ yl,
                           int* __restrict__ cnt,
                           int* __restrict__ list,
                           int cap) {
    int i = blockIdx.x * blockDim.x + threadIdx.x;
    if (i >= N) return;
    if (x[i] > 0.5f) {
        int idx = atomicAdd(cnt, 1);
        if (idx < cap) list[idx] = i;              // from w_in
    }
    if (yl[i] > 0.5f) {
        int idx = atomicAdd(cnt, 1);
        if (idx < cap) list[idx] = i | MAT_BIT;    // from w_rec
    }
}

// One wave (64 lanes) per output row: gather ~100 scattered 4B values from
// the row, butterfly-reduce, write y[row]. Sums of 1.0f are exact in fp32,
// so reduction order does not matter (deterministic).
__global__ void __launch_bounds__(256) spmv_rows(const float* __restrict__ w_in,
                                                 const float* __restrict__ w_rec,
                                                 const int* __restrict__ cnt,
                                                 const int* __restrict__ list,
                                                 float* __restrict__ y,
                                                 int cap) {
    int wave = (int)((blockIdx.x * blockDim.x + threadIdx.x) >> 6);
    int lane = threadIdx.x & 63;
    if (wave >= N) return;
    int n = cnt[0];
    if (n > cap) n = cap;

    size_t row_off = (size_t)wave * N;
    float s = 0.0f;
    for (int e = lane; e < n; e += 64) {
        int enc = list[e];
        int col = enc & (N - 1);
        const float* base = (enc & MAT_BIT) ? w_rec : w_in;
        s += base[row_off + col];
    }
    // wave64 butterfly reduction
    #pragma unroll
    for (int off = 32; off >= 1; off >>= 1)
        s += __shfl_xor(s, off, 64);
    if (lane == 0) y[wave] = s;
}

// Single block, 1024 threads. y values are exact small non-negative integers.
// Histogram -> threshold t (largest value with cum-from-top >= K) -> winners
// are all y > t plus the first (K - n_gt) indices (ascending) with y == t,
// matching jax.lax.top_k's stable (lowest-index-first) tie-break.
__global__ void __launch_bounds__(1024) kwta_kernel(const float* __restrict__ y,
                                                    float* __restrict__ out) {
    __shared__ int hist[1024];
    __shared__ int scan[1024];
    __shared__ int s_t, s_need;
    const int tid = threadIdx.x;
    const int CH = N / 1024;  // 16 contiguous elements per thread

    hist[tid] = 0;
    __syncthreads();

    int bins[CH];
    int base = tid * CH;
    #pragma unroll
    for (int i = 0; i < CH; ++i) {
        float v = y[base + i];
        int b = (int)v;
        if (b < 0) b = 0;
        if (b > 1023) b = 1023;
        bins[i] = b;
        atomicAdd(&hist[b], 1);
    }
    __syncthreads();

    if (tid == 0) {
        int cum = 0, t = 0, n_gt = 0;
        for (int b = 1023; b >= 0; --b) {
            int nc = cum + hist[b];
            if (nc >= K_ACTIVE) { t = b; n_gt = cum; break; }
            cum = nc;
        }
        s_t = t;
        s_need = K_ACTIVE - n_gt;
    }
    __syncthreads();

    const int t = s_t;
    const int need = s_need;

    // count equals-to-threshold in my chunk
    int c = 0;
    #pragma unroll
    for (int i = 0; i < CH; ++i) c += (bins[i] == t) ? 1 : 0;
    scan[tid] = c;
    __syncthreads();

    // Hillis-Steele inclusive scan over 1024 per-thread counts
    for (int off = 1; off < 1024; off <<= 1) {
        int v = scan[tid];
        int add = (tid >= off) ? scan[tid - off] : 0;
        __syncthreads();
        scan[tid] = v + add;
        __syncthreads();
    }
    int run = scan[tid] - c;  // exclusive prefix (index-ordered, chunks contiguous)

    #pragma unroll
    for (int i = 0; i < CH; ++i) {
        float o;
        if (bins[i] > t) {
            o = 1.0f;
        } else if (bins[i] == t) {
            o = (run < need) ? 1.0f : 0.0f;
            run++;
        } else {
            o = 0.0f;
        }
        out[base + i] = o;
    }
}

extern "C" void kernel_launch(void* const* d_in, const int* in_sizes, int n_in,
                              void* d_out, int out_size, void* d_ws, size_t ws_size,
                              hipStream_t stream) {
    const float* x     = (const float*)d_in[0];
    const float* ylat  = (const float*)d_in[1];
    const float* w_in  = (const float*)d_in[2];
    const float* w_rec = (const float*)d_in[3];
    float* out = (float*)d_out;

    char* ws = (char*)d_ws;
    int*   cnt  = (int*)ws;
    float* y    = (float*)(ws + 256);
    int*   list = (int*)(ws + 256 + N * sizeof(float));
    size_t used = 256 + (size_t)N * sizeof(float);
    long long cap_ll = (ws_size > used) ? (long long)((ws_size - used) / sizeof(int)) : 0;
    int cap = (cap_ll > 2LL * N) ? 2 * N : (int)cap_ll;

    init_counter<<<1, 64, 0, stream>>>(cnt);
    build_list<<<N / 256, 256, 0, stream>>>(x, ylat, cnt, list, cap);
    spmv_rows<<<N / 4, 256, 0, stream>>>(w_in, w_rec, cnt, list, y, cap);
    kwta_kernel<<<1, 1024, 0, stream>>>(y, out);
}

// Round 2
// 68.966 us; speedup vs baseline: 1.4963x; 1.4963x over previous
//
#include <hip/hip_runtime.h>

#define N 16384
#define K_ACTIVE 50
#define MAT_BIT (1 << 14)
#define NBINS 256
#define NCOPIES 32

// ws layout:
//   [0, 256)                 : int cnt
//   [256, 256+64K)           : float y[N]
//   [+32K)                   : int ghist[NCOPIES][NBINS]
//   [+128K)                  : int list[2N]

// Single block: zero ghist, build the combined active-column list via
// prefix-scan compaction (deterministic order), write count.
__global__ void __launch_bounds__(1024) build_all(const float* __restrict__ x,
                                                  const float* __restrict__ yl,
                                                  int* __restrict__ cnt,
                                                  int* __restrict__ list,
                                                  int* __restrict__ ghist,
                                                  int cap) {
    __shared__ int scan[1024];
    const int tid = threadIdx.x;
    for (int i = tid; i < NCOPIES * NBINS; i += 1024) ghist[i] = 0;
    const int base = tid * 16;
    int c = 0;
    #pragma unroll
    for (int i = 0; i < 16; ++i) {
        c += (x[base + i] > 0.5f) ? 1 : 0;
        c += (yl[base + i] > 0.5f) ? 1 : 0;
    }
    scan[tid] = c;
    __syncthreads();
    for (int off = 1; off < 1024; off <<= 1) {
        int v = scan[tid];
        int add = (tid >= off) ? scan[tid - off] : 0;
        __syncthreads();
        scan[tid] = v + add;
        __syncthreads();
    }
    int wr = scan[tid] - c;   // exclusive prefix, index-ordered
    #pragma unroll
    for (int i = 0; i < 16; ++i)
        if (x[base + i] > 0.5f) { if (wr < cap) list[wr] = base + i; wr++; }
    #pragma unroll
    for (int i = 0; i < 16; ++i)
        if (yl[base + i] > 0.5f) { if (wr < cap) list[wr] = (base + i) | MAT_BIT; wr++; }
    if (tid == 1023) cnt[0] = scan[1023];
}

// 2048 blocks x 256 threads (exactly 32 waves/CU). Each wave gathers 2 rows:
// 4 independent scattered loads in flight per lane. Per-block LDS histogram
// (8 values/block -> no contention), scattered into 32 global copies.
__global__ void __launch_bounds__(256) spmv_hist(const float* __restrict__ w_in,
                                                 const float* __restrict__ w_rec,
                                                 const int* __restrict__ cnt,
                                                 const int* __restrict__ list,
                                                 float* __restrict__ y,
                                                 int* __restrict__ ghist,
                                                 int cap) {
    __shared__ int hist[NBINS];
    const int tid = threadIdx.x;
    if (tid < NBINS) hist[tid] = 0;
    const int lane = tid & 63;
    const int wid = tid >> 6;
    const int row0 = blockIdx.x * 8 + wid * 2;
    const size_t off0 = (size_t)row0 * N;
    int n = cnt[0];
    if (n > cap) n = cap;

    float s0 = 0.f, s1 = 0.f;
    // first 128 entries unrolled (2 per lane), predicated
    if (lane < n) {
        int enc = list[lane];
        const float* b = (enc & MAT_BIT) ? w_rec : w_in;
        size_t a = off0 + (size_t)(enc & (N - 1));
        s0 += b[a];
        s1 += b[a + N];
    }
    if (lane + 64 < n) {
        int enc = list[lane + 64];
        const float* b = (enc & MAT_BIT) ? w_rec : w_in;
        size_t a = off0 + (size_t)(enc & (N - 1));
        s0 += b[a];
        s1 += b[a + N];
    }
    for (int e = 128 + lane; e < n; e += 64) {   // generic tail (rarely taken)
        int enc = list[e];
        const float* b = (enc & MAT_BIT) ? w_rec : w_in;
        size_t a = off0 + (size_t)(enc & (N - 1));
        s0 += b[a];
        s1 += b[a + N];
    }
    #pragma unroll
    for (int off = 32; off >= 1; off >>= 1) {
        s0 += __shfl_xor(s0, off, 64);
        s1 += __shfl_xor(s1, off, 64);
    }
    __syncthreads();   // hist zeroing complete
    if (lane == 0) {
        y[row0] = s0;
        y[row0 + 1] = s1;
        int b0 = (int)s0; b0 = b0 < 0 ? 0 : (b0 > NBINS - 1 ? NBINS - 1 : b0);
        int b1 = (int)s1; b1 = b1 < 0 ? 0 : (b1 > NBINS - 1 ? NBINS - 1 : b1);
        atomicAdd(&hist[b0], 1);
        atomicAdd(&hist[b1], 1);
    }
    __syncthreads();
    if (tid < NBINS) {
        int c = hist[tid];
        if (c) atomicAdd(&ghist[(blockIdx.x & (NCOPIES - 1)) * NBINS + tid], c);
    }
}

// Single block: sum hist copies, find threshold t + tie budget, then stable
// (lowest-index-first) tie-break output pass, matching jax.lax.top_k.
__global__ void __launch_bounds__(1024) finalize(const float* __restrict__ y,
                                                 const int* __restrict__ ghist,
                                                 float* __restrict__ out) {
    __shared__ int shist[NBINS];
    __shared__ int scan[1024];
    __shared__ int s_t, s_need;
    const int tid = threadIdx.x;
    if (tid < NBINS) {
        int s = 0;
        #pragma unroll
        for (int c = 0; c < NCOPIES; ++c) s += ghist[c * NBINS + tid];
        shist[tid] = s;
    }
    __syncthreads();
    if (tid == 0) {
        int cum = 0, t = 0, ngt = 0;
        for (int b = NBINS - 1; b >= 0; --b) {
            int nc = cum + shist[b];
            if (nc >= K_ACTIVE) { t = b; ngt = cum; break; }
            cum = nc;
        }
        s_t = t;
        s_need = K_ACTIVE - ngt;
    }
    __syncthreads();
    const int t = s_t, need = s_need;
    const int base = tid * 16;
    int bins[16];
    int c = 0;
    #pragma unroll
    for (int i = 0; i < 16; ++i) {
        int b = (int)y[base + i];
        bins[i] = b;
        c += (b == t) ? 1 : 0;
    }
    scan[tid] = c;
    __syncthreads();
    for (int off = 1; off < 1024; off <<= 1) {
        int v = scan[tid];
        int add = (tid >= off) ? scan[tid - off] : 0;
        __syncthreads();
        scan[tid] = v + add;
        __syncthreads();
    }
    int run = scan[tid] - c;   // exclusive prefix over index-ordered chunks
    #pragma unroll
    for (int i = 0; i < 16; ++i) {
        float o = 0.f;
        if (bins[i] > t) o = 1.f;
        else if (bins[i] == t) { if (run < need) o = 1.f; run++; }
        out[base + i] = o;
    }
}

extern "C" void kernel_launch(void* const* d_in, const int* in_sizes, int n_in,
                              void* d_out, int out_size, void* d_ws, size_t ws_size,
                              hipStream_t stream) {
    const float* x     = (const float*)d_in[0];
    const float* ylat  = (const float*)d_in[1];
    const float* w_in  = (const float*)d_in[2];
    const float* w_rec = (const float*)d_in[3];
    float* out = (float*)d_out;

    char* ws = (char*)d_ws;
    int*   cnt   = (int*)ws;
    float* y     = (float*)(ws + 256);
    int*   ghist = (int*)(ws + 256 + (size_t)N * sizeof(float));
    int*   list  = (int*)(ws + 256 + (size_t)N * sizeof(float)
                          + (size_t)NCOPIES * NBINS * sizeof(int));
    size_t used = 256 + (size_t)N * sizeof(float) + (size_t)NCOPIES * NBINS * sizeof(int);
    long long cap_ll = (ws_size > used) ? (long long)((ws_size - used) / sizeof(int)) : 0;
    int cap = (cap_ll > 2LL * N) ? 2 * N : (int)cap_ll;

    build_all<<<1, 1024, 0, stream>>>(x, ylat, cnt, list, ghist, cap);
    spmv_hist<<<N / 8, 256, 0, stream>>>(w_in, w_rec, cnt, list, y, ghist, cap);
    finalize<<<1, 1024, 0, stream>>>(y, ghist, out);
}